// Round 1
// baseline (728.178 us; speedup 1.0000x reference)
//
#include <hip/hip_runtime.h>

// Problem constants (fixed by setup_inputs)
constexpr int kB = 256;      // batch
constexpr int kN = 128;      // seq len
constexpr int kM = 512;      // mem width
constexpr int kSlots = 15;   // his_mem slots
constexpr int kS = 16;       // slots incl. null
constexpr int kW = 1536;     // attn_W row length (d_q + M)

// ---------------------------------------------------------------------------
// Generic 64x64-tile fp32 GEMM:  out[r][m] = sum_k A(r,k) * W[m][w_off+k] + add
// mode 0: A = global_trace (rows=256),  add = attn_b[m]
// mode 1: A = states (rows=32768),      add = Ag[r/128][m]   (Ag includes bias)
// mode 2: A = mem gather (rows=4096, r=b*16+s; s<15 -> his_mem, s=15 -> null_mem), add = 0
// ---------------------------------------------------------------------------
__global__ __launch_bounds__(256) void gemm_k(
    const float* __restrict__ A, const float* __restrict__ W,
    const float* __restrict__ addv, float* __restrict__ out,
    int w_off, int mode,
    const float* __restrict__ his_mem, const float* __restrict__ null_mem)
{
    __shared__ float As[16 * 68];   // [k][r], stride 68 -> 2-way max bank conflict
    __shared__ float Bs[16 * 68];   // [k][m]
    const int r0 = blockIdx.x * 64;
    const int n0 = blockIdx.y * 64;
    const int tid = threadIdx.x;
    const int row_l = tid >> 2;           // 0..63
    const int k4 = (tid & 3) * 4;         // 0,4,8,12
    const int ty = tid >> 4, tx = tid & 15;

    const float* ap;
    if (mode == 2) {
        int r = r0 + row_l;
        int b = r >> 4, s = r & 15;
        ap = (s < kSlots) ? (his_mem + (size_t)(b * kSlots + s) * kM)
                          : (null_mem + (size_t)b * kM);
    } else {
        ap = A + (size_t)(r0 + row_l) * kM;
    }
    const float* wp = W + (size_t)(n0 + row_l) * kW + w_off;

    float acc[4][4];
#pragma unroll
    for (int i = 0; i < 4; ++i)
#pragma unroll
        for (int j = 0; j < 4; ++j) acc[i][j] = 0.f;

    for (int kt = 0; kt < kM; kt += 16) {
        float4 a4 = *(const float4*)(ap + kt + k4);
        float4 b4 = *(const float4*)(wp + kt + k4);
        __syncthreads();
        As[(k4 + 0) * 68 + row_l] = a4.x; As[(k4 + 1) * 68 + row_l] = a4.y;
        As[(k4 + 2) * 68 + row_l] = a4.z; As[(k4 + 3) * 68 + row_l] = a4.w;
        Bs[(k4 + 0) * 68 + row_l] = b4.x; Bs[(k4 + 1) * 68 + row_l] = b4.y;
        Bs[(k4 + 2) * 68 + row_l] = b4.z; Bs[(k4 + 3) * 68 + row_l] = b4.w;
        __syncthreads();
#pragma unroll
        for (int k = 0; k < 16; ++k) {
            const float4 av = *(const float4*)&As[k * 68 + ty * 4];
            const float4 bv = *(const float4*)&Bs[k * 68 + tx * 4];
            acc[0][0] = fmaf(av.x, bv.x, acc[0][0]);
            acc[0][1] = fmaf(av.x, bv.y, acc[0][1]);
            acc[0][2] = fmaf(av.x, bv.z, acc[0][2]);
            acc[0][3] = fmaf(av.x, bv.w, acc[0][3]);
            acc[1][0] = fmaf(av.y, bv.x, acc[1][0]);
            acc[1][1] = fmaf(av.y, bv.y, acc[1][1]);
            acc[1][2] = fmaf(av.y, bv.z, acc[1][2]);
            acc[1][3] = fmaf(av.y, bv.w, acc[1][3]);
            acc[2][0] = fmaf(av.z, bv.x, acc[2][0]);
            acc[2][1] = fmaf(av.z, bv.y, acc[2][1]);
            acc[2][2] = fmaf(av.z, bv.z, acc[2][2]);
            acc[2][3] = fmaf(av.z, bv.w, acc[2][3]);
            acc[3][0] = fmaf(av.w, bv.x, acc[3][0]);
            acc[3][1] = fmaf(av.w, bv.y, acc[3][1]);
            acc[3][2] = fmaf(av.w, bv.z, acc[3][2]);
            acc[3][3] = fmaf(av.w, bv.w, acc[3][3]);
        }
    }

    float4 addv4 = make_float4(0.f, 0.f, 0.f, 0.f);
    if (mode == 0)      addv4 = *(const float4*)(addv + n0 + tx * 4);
    else if (mode == 1) addv4 = *(const float4*)(addv + (size_t)(r0 >> 7) * kM + n0 + tx * 4);

#pragma unroll
    for (int i = 0; i < 4; ++i) {
        float4 o;
        o.x = acc[i][0] + addv4.x;
        o.y = acc[i][1] + addv4.y;
        o.z = acc[i][2] + addv4.z;
        o.w = acc[i][3] + addv4.w;
        *(float4*)(out + (size_t)(r0 + ty * 4 + i) * kM + n0 + tx * 4) = o;
    }
}

// ---------------------------------------------------------------------------
// Empty-slot flags: flags[b*16+s] = (sum |mem[b,s,:]| == 0)
// ---------------------------------------------------------------------------
__global__ __launch_bounds__(256) void empty_k(
    const float* __restrict__ his_mem, const float* __restrict__ null_mem,
    int* __restrict__ flags)
{
    int wave = threadIdx.x >> 6;
    int lane = threadIdx.x & 63;
    int row = blockIdx.x * 4 + wave;           // 0..4095
    int b = row >> 4, s = row & 15;
    const float* p = (s < kSlots) ? his_mem + (size_t)(b * kSlots + s) * kM
                                  : null_mem + (size_t)b * kM;
    int nz = 0;
    for (int j = 0; j < kM; j += 64) nz |= (p[j + lane] != 0.f);
    unsigned long long bal = __ballot(nz);
    if (lane == 0) flags[row] = (bal != 0ull) ? 0 : 1;
}

// ---------------------------------------------------------------------------
// Sequential scan, one block per batch b. C[s][:] cached in LDS, updated only
// on (rare) write events.
// ---------------------------------------------------------------------------
__device__ __forceinline__ float tanh_fast(float x)
{
    float xc = fminf(15.f, fmaxf(-15.f, x));
    float ex = __expf(2.f * xc);
    return 1.f - 2.f * __builtin_amdgcn_rcpf(ex + 1.f);
}

constexpr int kCsStride = 528;   // 512 + 16 -> 2-way max bank conflict

__global__ __launch_bounds__(256) void scan_k(
    const float* __restrict__ Q,        // [B*n, 512]  (ws)
    const float* __restrict__ C0,       // [B*16, 512] (ws)
    const int*   __restrict__ empty0,   // [B*16]      (ws)
    const float* __restrict__ states,   // [B, n, 512]
    const float* __restrict__ his_mem,  // [B, 15, 512]
    const float* __restrict__ states_mask, // [B, n]
    const float* __restrict__ gumbel_u, // [B, n, 16]
    const float* __restrict__ W,        // [512, 1536]
    const float* __restrict__ v,        // [512]
    float* __restrict__ out)            // hm_final [B*15*512] ++ write_log [B*n*16]
{
    const int b = blockIdx.x;
    const int tid = threadIdx.x;

    __shared__ float Cs[kS * kCsStride];
    __shared__ float Qs[kM];
    __shared__ float vs[kM];
    __shared__ float Ss[kM];
    __shared__ float e_sh[kS];
    __shared__ float empty_sh[kS];
    __shared__ int   slot_src[kSlots];
    __shared__ int   wk_sh;
    __shared__ int   nz_sh;

    // prologue: load C0, v, flags
    for (int i = tid; i < kS * kM; i += 256) {
        int s = i >> 9, m = i & 511;
        Cs[s * kCsStride + m] = C0[(size_t)(b * kS + s) * kM + m];
    }
    for (int i = tid; i < kM; i += 256) vs[i] = v[i];
    if (tid < kS) empty_sh[tid] = empty0[b * kS + tid] ? 1.0f : 0.0f;
    if (tid < kSlots) slot_src[tid] = -1;
    __syncthreads();

    const int sidx = tid >> 4;   // slot this thread works on
    const int ml = tid & 15;     // lane within slot group

    // prefetch Q row 0
    float q0 = Q[(size_t)(b * kN) * kM + tid];
    float q1 = Q[(size_t)(b * kN) * kM + tid + 256];

    float* out_hm = out;
    float* out_log = out + (size_t)kB * kSlots * kM;

    for (int t = 0; t < kN; ++t) {
        Qs[tid] = q0; Qs[tid + 256] = q1;
        __syncthreads();
        if (t + 1 < kN) {
            q0 = Q[(size_t)(b * kN + t + 1) * kM + tid];
            q1 = Q[(size_t)(b * kN + t + 1) * kM + tid + 256];
        }

        // e[s] = sum_m v[m] * tanh(Q[m] + C[s][m])
        const float* crow = &Cs[sidx * kCsStride];
        float a0 = 0.f, a1 = 0.f;
#pragma unroll 8
        for (int j = 0; j < 32; ++j) {
            int m = ml + j * 16;
            float x = Qs[m] + crow[m];
            float th = tanh_fast(x);
            if (j & 1) a1 = fmaf(vs[m], th, a1);
            else       a0 = fmaf(vs[m], th, a0);
        }
        float e = a0 + a1;
        e += __shfl_xor(e, 1); e += __shfl_xor(e, 2);
        e += __shfl_xor(e, 4); e += __shfl_xor(e, 8);
        if (ml == 0) e_sh[sidx] = e;
        __syncthreads();

        // wave 0: softmax + empty mask + gumbel + argmax
        if (tid < 64) {
            int s = tid;
            float ev = (s < kS) ? e_sh[s] : -3.0e38f;
            float mx = ev;
            mx = fmaxf(mx, __shfl_xor(mx, 1));
            mx = fmaxf(mx, __shfl_xor(mx, 2));
            mx = fmaxf(mx, __shfl_xor(mx, 4));
            mx = fmaxf(mx, __shfl_xor(mx, 8));
            float w = (s < kS) ? __expf(ev - mx) : 0.f;
            float sm = w;
            sm += __shfl_xor(sm, 1); sm += __shfl_xor(sm, 2);
            sm += __shfl_xor(sm, 4); sm += __shfl_xor(sm, 8);
            w = w / sm;
            w += 10.0f * ((s < kS) ? empty_sh[s] : 0.f);
            float z;
            if (s < kS) {
                float u = gumbel_u[(size_t)(b * kN + t) * kS + s];
                u = fminf(fmaxf(u, 1e-20f), 1.0f);
                float g = -logf(-logf(u) + 1e-20f);
                z = w + g;            // tau = 1.0
            } else z = -3.0e38f;
            float zm = z;
            zm = fmaxf(zm, __shfl_xor(zm, 1));
            zm = fmaxf(zm, __shfl_xor(zm, 2));
            zm = fmaxf(zm, __shfl_xor(zm, 4));
            zm = fmaxf(zm, __shfl_xor(zm, 8));
            unsigned long long bal = __ballot(z == zm) & 0xFFFFull;
            int k = __ffsll(bal) - 1;   // first-max index (jnp.argmax semantics)
            if (s < kS) out_log[(size_t)(b * kN + t) * kS + s] = (s == k) ? 1.0f : 0.0f;
            if (s == 0) {
                float mv = states_mask[b * kN + t];
                wk_sh = (k < kSlots && mv != 0.0f) ? k : -1;
                nz_sh = 0;
            }
        }
        __syncthreads();

        int wk = wk_sh;
        if (wk >= 0) {
            // stage state row + nonzero detect
            float s0v = states[(size_t)(b * kN + t) * kM + tid];
            float s1v = states[(size_t)(b * kN + t) * kM + tid + 256];
            Ss[tid] = s0v; Ss[tid + 256] = s1v;
            if (s0v != 0.f || s1v != 0.f) nz_sh = 1;
            __syncthreads();
            // C[wk][m] = sum_k W3[m][k] * state[k]
            const float* w3a = W + (size_t)tid * kW + 1024;
            const float* w3b = W + (size_t)(tid + 256) * kW + 1024;
            float ca = 0.f, cb = 0.f;
#pragma unroll 4
            for (int kk = 0; kk < kM; kk += 4) {
                float4 wa = *(const float4*)(w3a + kk);
                float4 wb = *(const float4*)(w3b + kk);
                float4 sv = *(const float4*)&Ss[kk];
                ca = fmaf(wa.x, sv.x, ca); ca = fmaf(wa.y, sv.y, ca);
                ca = fmaf(wa.z, sv.z, ca); ca = fmaf(wa.w, sv.w, ca);
                cb = fmaf(wb.x, sv.x, cb); cb = fmaf(wb.y, sv.y, cb);
                cb = fmaf(wb.z, sv.z, cb); cb = fmaf(wb.w, sv.w, cb);
            }
            Cs[wk * kCsStride + tid] = ca;
            Cs[wk * kCsStride + tid + 256] = cb;
            __syncthreads();
            if (tid == 0) {
                slot_src[wk] = t;
                empty_sh[wk] = nz_sh ? 0.f : 1.f;
            }
        }
        __syncthreads();
    }

    // epilogue: hm_final
    for (int s = 0; s < kSlots; ++s) {
        int ts = slot_src[s];
        const float* src = (ts >= 0) ? (states + (size_t)(b * kN + ts) * kM)
                                     : (his_mem + (size_t)(b * kSlots + s) * kM);
        out_hm[(size_t)(b * kSlots + s) * kM + tid] = src[tid];
        out_hm[(size_t)(b * kSlots + s) * kM + tid + 256] = src[tid + 256];
    }
}

// ---------------------------------------------------------------------------
extern "C" void kernel_launch(void* const* d_in, const int* in_sizes, int n_in,
                              void* d_out, int out_size, void* d_ws, size_t ws_size,
                              hipStream_t stream)
{
    const float* his_mem      = (const float*)d_in[0];
    const float* states       = (const float*)d_in[1];
    const float* states_mask  = (const float*)d_in[2];
    const float* global_trace = (const float*)d_in[3];
    const float* null_mem     = (const float*)d_in[4];
    const float* gumbel_u     = (const float*)d_in[5];
    const float* attn_W       = (const float*)d_in[6];
    const float* attn_b       = (const float*)d_in[7];
    const float* v            = (const float*)d_in[8];

    // workspace layout (fp32): Ag[256*512] | Q[32768*512] | C0[4096*512] | empty[4096]
    float* Ag = (float*)d_ws;
    float* Q  = Ag + (size_t)kB * kM;
    float* C0 = Q + (size_t)kB * kN * kM;
    int* empty0 = (int*)(C0 + (size_t)kB * kS * kM);
    // total: ~72.5 MiB; assumes ws_size is at least that.

    // Ag[b][m] = W[:,512:1024] @ global_trace[b] + attn_b
    gemm_k<<<dim3(kB / 64, kM / 64), 256, 0, stream>>>(
        global_trace, attn_W, attn_b, Ag, 512, 0, nullptr, nullptr);
    // Q[b*n+t][m] = W[:,0:512] @ states[b,t] + Ag[b]
    gemm_k<<<dim3(kB * kN / 64, kM / 64), 256, 0, stream>>>(
        states, attn_W, Ag, Q, 0, 1, nullptr, nullptr);
    // C0[b*16+s][m] = W[:,1024:1536] @ mem[b,s]
    gemm_k<<<dim3(kB * kS / 64, kM / 64), 256, 0, stream>>>(
        nullptr, attn_W, nullptr, C0, 1024, 2, his_mem, null_mem);
    // empty flags
    empty_k<<<kB * kS / 4, 256, 0, stream>>>(his_mem, null_mem, empty0);
    // sequential scan
    scan_k<<<kB, 256, 0, stream>>>(Q, C0, empty0, states, his_mem, states_mask,
                                   gumbel_u, attn_W, v, (float*)d_out);
}

// Round 2
// 378.513 us; speedup vs baseline: 1.9238x; 1.9238x over previous
//
#include <hip/hip_runtime.h>

// Problem constants (fixed by setup_inputs)
constexpr int kB = 256;      // batch
constexpr int kN = 128;      // seq len
constexpr int kM = 512;      // mem width
constexpr int kSlots = 15;   // his_mem slots
constexpr int kS = 16;       // slots incl. null
constexpr int kW = 1536;     // attn_W row length (d_q + M)

// ---------------------------------------------------------------------------
// Empty-slot flags: flags[b*16+s] = (sum |mem[b,s,:]| == 0). Also zeroes cnt.
// ---------------------------------------------------------------------------
__global__ __launch_bounds__(256) void empty_k(
    const float* __restrict__ his_mem, const float* __restrict__ null_mem,
    int* __restrict__ flags, int* __restrict__ cnt)
{
    if (blockIdx.x == 0) cnt[threadIdx.x] = 0;   // kB == 256 == blockDim
    int wave = threadIdx.x >> 6;
    int lane = threadIdx.x & 63;
    int row = blockIdx.x * 4 + wave;             // 0..4095
    int b = row >> 4, s = row & 15;
    const float* p = (s < kSlots) ? his_mem + (size_t)(b * kSlots + s) * kM
                                  : null_mem + (size_t)b * kM;
    int nz = 0;
    for (int j = 0; j < kM; j += 64) nz |= (p[j + lane] != 0.f);
    unsigned long long bal = __ballot(nz);
    if (lane == 0) flags[row] = (bal != 0ull) ? 0 : 1;
}

// ---------------------------------------------------------------------------
// Filter: per (b,t) decide from gumbel noise alone whether argmax could be
// anything other than the null slot (15). w in (0,1) strictly, so
// z_k <= g_k + 10*empty_k + 1 and z_15 >= g_15 + 10*empty_15. Ambiguous iff
// some k<15 can reach z_15's lower bound (with 0.01 fp margin).
// Writes default one-hot(15) log rows; resolver overwrites ambiguous rows.
// ---------------------------------------------------------------------------
__global__ __launch_bounds__(256) void filter_k(
    const float* __restrict__ gumbel_u, const int* __restrict__ empty0,
    float* __restrict__ out_log, unsigned char* __restrict__ amb_flags,
    int* __restrict__ cnt)
{
    int idx = blockIdx.x * 256 + threadIdx.x;    // b*128 + t
    int b = idx >> 7;
    const float* up = gumbel_u + (size_t)idx * kS;
    float g[kS];
#pragma unroll
    for (int s = 0; s < kS; ++s) {
        float u = up[s];
        u = fminf(fmaxf(u, 1e-20f), 1.0f);
        g[s] = -logf(-logf(u) + 1e-20f);
    }
    float e15 = empty0[b * kS + 15] ? 1.f : 0.f;
    float rhs = g[15] + 10.f * e15 - 1.01f;      // ambiguous iff g_k+10*ek >= rhs
    bool amb = false;
#pragma unroll
    for (int s = 0; s < kSlots; ++s) {
        float ek = empty0[b * kS + s] ? 1.f : 0.f;
        amb = amb || (g[s] + 10.f * ek >= rhs);
    }
    amb_flags[idx] = amb ? 1 : 0;
    if (amb) atomicAdd(&cnt[b], 1);
    float* lp = out_log + (size_t)idx * kS;
    float4 zz = make_float4(0.f, 0.f, 0.f, 0.f);
    *(float4*)(lp + 0) = zz;
    *(float4*)(lp + 4) = zz;
    *(float4*)(lp + 8) = zz;
    *(float4*)(lp + 12) = make_float4(0.f, 0.f, 0.f, 1.f);
}

// ---------------------------------------------------------------------------
// C0[b*16+s][m] = W[m][1024:1536] . mem[b,s]  — only for batches with
// ambiguous steps (early-exit per 64-row block covering 4 batches).
// ---------------------------------------------------------------------------
__global__ __launch_bounds__(256) void c0_k(
    const float* __restrict__ W, const float* __restrict__ his_mem,
    const float* __restrict__ null_mem, const int* __restrict__ cnt,
    float* __restrict__ C0)
{
    const int r0 = blockIdx.x * 64;              // rows r = b*16+s
    const int b0 = r0 >> 4;                      // covers batches b0..b0+3
    if (cnt[b0] == 0 && cnt[b0 + 1] == 0 && cnt[b0 + 2] == 0 && cnt[b0 + 3] == 0)
        return;
    __shared__ float As[16 * 68];
    __shared__ float Bs[16 * 68];
    const int n0 = blockIdx.y * 64;
    const int tid = threadIdx.x;
    const int row_l = tid >> 2;
    const int k4 = (tid & 3) * 4;
    const int ty = tid >> 4, tx = tid & 15;

    int r = r0 + row_l;
    int b = r >> 4, s = r & 15;
    const float* ap = (s < kSlots) ? (his_mem + (size_t)(b * kSlots + s) * kM)
                                   : (null_mem + (size_t)b * kM);
    const float* wp = W + (size_t)(n0 + row_l) * kW + 1024;

    float acc[4][4];
#pragma unroll
    for (int i = 0; i < 4; ++i)
#pragma unroll
        for (int j = 0; j < 4; ++j) acc[i][j] = 0.f;

    for (int kt = 0; kt < kM; kt += 16) {
        float4 a4 = *(const float4*)(ap + kt + k4);
        float4 b4 = *(const float4*)(wp + kt + k4);
        __syncthreads();
        As[(k4 + 0) * 68 + row_l] = a4.x; As[(k4 + 1) * 68 + row_l] = a4.y;
        As[(k4 + 2) * 68 + row_l] = a4.z; As[(k4 + 3) * 68 + row_l] = a4.w;
        Bs[(k4 + 0) * 68 + row_l] = b4.x; Bs[(k4 + 1) * 68 + row_l] = b4.y;
        Bs[(k4 + 2) * 68 + row_l] = b4.z; Bs[(k4 + 3) * 68 + row_l] = b4.w;
        __syncthreads();
#pragma unroll
        for (int k = 0; k < 16; ++k) {
            const float4 av = *(const float4*)&As[k * 68 + ty * 4];
            const float4 bv = *(const float4*)&Bs[k * 68 + tx * 4];
            acc[0][0] = fmaf(av.x, bv.x, acc[0][0]);
            acc[0][1] = fmaf(av.x, bv.y, acc[0][1]);
            acc[0][2] = fmaf(av.x, bv.z, acc[0][2]);
            acc[0][3] = fmaf(av.x, bv.w, acc[0][3]);
            acc[1][0] = fmaf(av.y, bv.x, acc[1][0]);
            acc[1][1] = fmaf(av.y, bv.y, acc[1][1]);
            acc[1][2] = fmaf(av.y, bv.z, acc[1][2]);
            acc[1][3] = fmaf(av.y, bv.w, acc[1][3]);
            acc[2][0] = fmaf(av.z, bv.x, acc[2][0]);
            acc[2][1] = fmaf(av.z, bv.y, acc[2][1]);
            acc[2][2] = fmaf(av.z, bv.z, acc[2][2]);
            acc[2][3] = fmaf(av.z, bv.w, acc[2][3]);
            acc[3][0] = fmaf(av.w, bv.x, acc[3][0]);
            acc[3][1] = fmaf(av.w, bv.y, acc[3][1]);
            acc[3][2] = fmaf(av.w, bv.z, acc[3][2]);
            acc[3][3] = fmaf(av.w, bv.w, acc[3][3]);
        }
    }
#pragma unroll
    for (int i = 0; i < 4; ++i) {
        float4 o = make_float4(acc[i][0], acc[i][1], acc[i][2], acc[i][3]);
        *(float4*)(C0 + (size_t)(r0 + ty * 4 + i) * kM + n0 + tx * 4) = o;
    }
}

// ---------------------------------------------------------------------------
// Resolver: one block per batch; replays only the ambiguous steps exactly.
// ---------------------------------------------------------------------------
__device__ __forceinline__ float tanh_fast(float x)
{
    float xc = fminf(15.f, fmaxf(-15.f, x));
    float ex = __expf(2.f * xc);
    return 1.f - 2.f * __builtin_amdgcn_rcpf(ex + 1.f);
}

constexpr int kCsStride = 528;   // 512 + 16 -> at most 2-way bank aliasing (free)

__global__ __launch_bounds__(256) void resolve_k(
    const float* __restrict__ C0, const int* __restrict__ empty0,
    const unsigned char* __restrict__ amb_flags, const int* __restrict__ cnt,
    const float* __restrict__ states, const float* __restrict__ his_mem,
    const float* __restrict__ states_mask, const float* __restrict__ gumbel_u,
    const float* __restrict__ global_trace, const float* __restrict__ W,
    const float* __restrict__ attn_b, const float* __restrict__ v,
    float* __restrict__ out)
{
    const int b = blockIdx.x;
    const int tid = threadIdx.x;
    float* out_hm = out;
    float* out_log = out + (size_t)kB * kSlots * kM;

    const int nc = cnt[b];
    if (nc == 0) {
        // no ambiguous steps: hm_final == his_mem, log already written by filter
        for (int s = 0; s < kSlots; ++s) {
            const float* src = his_mem + (size_t)(b * kSlots + s) * kM;
            float* dst = out_hm + (size_t)(b * kSlots + s) * kM;
            dst[tid] = src[tid];
            dst[tid + 256] = src[tid + 256];
        }
        return;
    }

    __shared__ float Cs[kS * kCsStride];
    __shared__ float Xs[1024];          // [state(512) | global_trace(512)]
    __shared__ float qs[kM];
    __shared__ float vs[kM];
    __shared__ float bs[kM];
    __shared__ float e_sh[kS];
    __shared__ float empty_sh[kS];
    __shared__ unsigned char flS[kN];
    __shared__ int slot_src[kSlots];
    __shared__ int wk_sh, nz_sh;

    for (int i = tid; i < kS * kM; i += 256) {
        int s = i >> 9, m = i & 511;
        Cs[s * kCsStride + m] = C0[(size_t)(b * kS + s) * kM + m];
    }
    for (int i = tid; i < kM; i += 256) {
        vs[i] = v[i];
        bs[i] = attn_b[i];
        Xs[512 + i] = global_trace[(size_t)b * kM + i];
    }
    if (tid < kS) empty_sh[tid] = empty0[b * kS + tid] ? 1.0f : 0.0f;
    if (tid < kSlots) slot_src[tid] = -1;
    if (tid < kN) flS[tid] = amb_flags[b * kN + tid];
    __syncthreads();

    const int sidx = tid >> 4;
    const int ml = tid & 15;

    for (int t = 0; t < kN; ++t) {
        if (!flS[t]) continue;   // uniform per block

        // stage state row
        Xs[tid] = states[(size_t)(b * kN + t) * kM + tid];
        Xs[tid + 256] = states[(size_t)(b * kN + t) * kM + tid + 256];
        __syncthreads();

        // q[m] = bias[m] + W[m][0:1024] . [state|gt]
        const float* wra = W + (size_t)tid * kW;
        const float* wrb = W + (size_t)(tid + 256) * kW;
        float qa = bs[tid], qb = bs[tid + 256];
#pragma unroll 4
        for (int k = 0; k < 1024; k += 4) {
            float4 wa = *(const float4*)(wra + k);
            float4 wb = *(const float4*)(wrb + k);
            float4 xv = *(const float4*)&Xs[k];
            qa = fmaf(wa.x, xv.x, qa); qa = fmaf(wa.y, xv.y, qa);
            qa = fmaf(wa.z, xv.z, qa); qa = fmaf(wa.w, xv.w, qa);
            qb = fmaf(wb.x, xv.x, qb); qb = fmaf(wb.y, xv.y, qb);
            qb = fmaf(wb.z, xv.z, qb); qb = fmaf(wb.w, xv.w, qb);
        }
        qs[tid] = qa; qs[tid + 256] = qb;
        __syncthreads();

        // e[s] = sum_m v[m] * tanh(q[m] + C[s][m])
        const float* crow = &Cs[sidx * kCsStride];
        float a0 = 0.f, a1 = 0.f;
#pragma unroll 8
        for (int j = 0; j < 32; ++j) {
            int m = ml + j * 16;
            float x = qs[m] + crow[m];
            float th = tanh_fast(x);
            if (j & 1) a1 = fmaf(vs[m], th, a1);
            else       a0 = fmaf(vs[m], th, a0);
        }
        float e = a0 + a1;
        e += __shfl_xor(e, 1); e += __shfl_xor(e, 2);
        e += __shfl_xor(e, 4); e += __shfl_xor(e, 8);
        if (ml == 0) e_sh[sidx] = e;
        __syncthreads();

        // wave 0: softmax + empty mask + gumbel + argmax
        if (tid < 64) {
            int s = tid;
            float ev = (s < kS) ? e_sh[s] : -3.0e38f;
            float mx = ev;
            mx = fmaxf(mx, __shfl_xor(mx, 1));
            mx = fmaxf(mx, __shfl_xor(mx, 2));
            mx = fmaxf(mx, __shfl_xor(mx, 4));
            mx = fmaxf(mx, __shfl_xor(mx, 8));
            float w = (s < kS) ? __expf(ev - mx) : 0.f;
            float sm = w;
            sm += __shfl_xor(sm, 1); sm += __shfl_xor(sm, 2);
            sm += __shfl_xor(sm, 4); sm += __shfl_xor(sm, 8);
            w = w / sm;
            w += 10.0f * ((s < kS) ? empty_sh[s] : 0.f);
            float z;
            if (s < kS) {
                float u = gumbel_u[(size_t)(b * kN + t) * kS + s];
                u = fminf(fmaxf(u, 1e-20f), 1.0f);
                float g = -logf(-logf(u) + 1e-20f);
                z = w + g;            // tau = 1.0
            } else z = -3.0e38f;
            float zm = z;
            zm = fmaxf(zm, __shfl_xor(zm, 1));
            zm = fmaxf(zm, __shfl_xor(zm, 2));
            zm = fmaxf(zm, __shfl_xor(zm, 4));
            zm = fmaxf(zm, __shfl_xor(zm, 8));
            unsigned long long bal = __ballot(z == zm) & 0xFFFFull;
            int k = __ffsll(bal) - 1;   // first-max (jnp.argmax semantics)
            if (s < kS) out_log[(size_t)(b * kN + t) * kS + s] = (s == k) ? 1.0f : 0.0f;
            if (s == 0) {
                float mv = states_mask[b * kN + t];
                wk_sh = (k < kSlots && mv != 0.0f) ? k : -1;
                nz_sh = 0;
            }
        }
        __syncthreads();

        int wk = wk_sh;
        if (wk >= 0) {
            if (Xs[tid] != 0.f || Xs[tid + 256] != 0.f) nz_sh = 1;
            // C[wk][m] = W[m][1024:1536] . state
            const float* w3a = W + (size_t)tid * kW + 1024;
            const float* w3b = W + (size_t)(tid + 256) * kW + 1024;
            float ca = 0.f, cb = 0.f;
#pragma unroll 4
            for (int kk = 0; kk < kM; kk += 4) {
                float4 wa = *(const float4*)(w3a + kk);
                float4 wb = *(const float4*)(w3b + kk);
                float4 sv = *(const float4*)&Xs[kk];
                ca = fmaf(wa.x, sv.x, ca); ca = fmaf(wa.y, sv.y, ca);
                ca = fmaf(wa.z, sv.z, ca); ca = fmaf(wa.w, sv.w, ca);
                cb = fmaf(wb.x, sv.x, cb); cb = fmaf(wb.y, sv.y, cb);
                cb = fmaf(wb.z, sv.z, cb); cb = fmaf(wb.w, sv.w, cb);
            }
            Cs[wk * kCsStride + tid] = ca;
            Cs[wk * kCsStride + tid + 256] = cb;
            __syncthreads();
            if (tid == 0) {
                slot_src[wk] = t;
                empty_sh[wk] = nz_sh ? 0.f : 1.f;
            }
        }
        __syncthreads();
    }

    // epilogue: hm_final
    for (int s = 0; s < kSlots; ++s) {
        int ts = slot_src[s];
        const float* src = (ts >= 0) ? (states + (size_t)(b * kN + ts) * kM)
                                     : (his_mem + (size_t)(b * kSlots + s) * kM);
        float* dst = out_hm + (size_t)(b * kSlots + s) * kM;
        dst[tid] = src[tid];
        dst[tid + 256] = src[tid + 256];
    }
}

// ---------------------------------------------------------------------------
extern "C" void kernel_launch(void* const* d_in, const int* in_sizes, int n_in,
                              void* d_out, int out_size, void* d_ws, size_t ws_size,
                              hipStream_t stream)
{
    const float* his_mem      = (const float*)d_in[0];
    const float* states       = (const float*)d_in[1];
    const float* states_mask  = (const float*)d_in[2];
    const float* global_trace = (const float*)d_in[3];
    const float* null_mem     = (const float*)d_in[4];
    const float* gumbel_u     = (const float*)d_in[5];
    const float* attn_W       = (const float*)d_in[6];
    const float* attn_b       = (const float*)d_in[7];
    const float* v            = (const float*)d_in[8];

    // ws layout: C0[4096*512] f32 | empty0[4096] i32 | cnt[256] i32 | amb[32768] u8
    float* C0 = (float*)d_ws;
    int* empty0 = (int*)(C0 + (size_t)kB * kS * kM);
    int* cnt = empty0 + kB * kS;
    unsigned char* amb = (unsigned char*)(cnt + kB);

    empty_k<<<kB * kS / 4, 256, 0, stream>>>(his_mem, null_mem, empty0, cnt);
    filter_k<<<kB * kN / 256, 256, 0, stream>>>(gumbel_u, empty0, (float*)d_out + (size_t)kB * kSlots * kM, amb, cnt);
    c0_k<<<dim3(kB * kS / 64, kM / 64), 256, 0, stream>>>(attn_W, his_mem, null_mem, cnt, C0);
    resolve_k<<<kB, 256, 0, stream>>>(C0, empty0, amb, cnt, states, his_mem,
                                      states_mask, gumbel_u, global_trace,
                                      attn_W, attn_b, v, (float*)d_out);
}